// Round 14
// baseline (732.377 us; speedup 1.0000x reference)
//
#include <hip/hip_runtime.h>
#include <hip/hip_bf16.h>
#include <stdint.h>

typedef __bf16 bf16x8 __attribute__((ext_vector_type(8)));
typedef float  f32x4  __attribute__((ext_vector_type(4)));
typedef unsigned short u16;

__device__ __forceinline__ u16 f2bf(float f) {
    return __builtin_bit_cast(u16, __float2bfloat16(f));
}

__device__ __forceinline__ void gload16(const void* g, void* l) {
    __builtin_amdgcn_global_load_lds(
        (const __attribute__((address_space(1))) void*)g,
        (__attribute__((address_space(3))) void*)l,
        16, 0, 0);
}

// ---------------- quantization pipeline ----------------

__global__ void zero3_k(unsigned int* p) {
    if (threadIdx.x < 3) p[threadIdx.x] = 0u;
}

__global__ void maxabs_k(const float* __restrict__ w, int n, unsigned int* __restrict__ out) {
    const int tid = threadIdx.x;
    float m = 0.f;
    for (int i = blockIdx.x * blockDim.x + tid; i < n; i += gridDim.x * blockDim.x)
        m = fmaxf(m, fabsf(w[i]));
    #pragma unroll
    for (int off = 32; off > 0; off >>= 1)
        m = fmaxf(m, __shfl_down(m, off));
    __shared__ float red[4];
    if ((tid & 63) == 0) red[tid >> 6] = m;
    __syncthreads();
    if (tid == 0) {
        m = fmaxf(fmaxf(red[0], red[1]), fmaxf(red[2], red[3]));
        atomicMax(out, __float_as_uint(m));  // all values >=0: uint order == float order
    }
}

// w_q = clip(rint(w/scale), -n, n) * scale, scale = max|w|/n  (all fp32, matches jnp)
__global__ void quant_k(const float* __restrict__ w, int n,
                        const unsigned int* __restrict__ maxbits, float qn,
                        u16* __restrict__ out) {
    const float scale = __uint_as_float(*maxbits) / qn;
    for (int i = blockIdx.x * blockDim.x + threadIdx.x; i < n; i += gridDim.x * blockDim.x) {
        float q = rintf(w[i] / scale);          // RNE == jnp.round
        q = fminf(qn, fmaxf(-qn, q));
        out[i] = f2bf(q * scale);
    }
}

__global__ void cvt_k(const float* __restrict__ x, u16* __restrict__ o, long n) {
    const long stride = (long)gridDim.x * blockDim.x * 4;
    for (long i = ((long)blockIdx.x * blockDim.x + threadIdx.x) * 4; i < n; i += stride) {
        float4 v = *(const float4*)(x + i);
        unsigned int lo = (unsigned int)f2bf(v.x) | ((unsigned int)f2bf(v.y) << 16);
        unsigned int hi = (unsigned int)f2bf(v.z) | ((unsigned int)f2bf(v.w) << 16);
        *(uint2*)(o + i) = make_uint2(lo, hi);
    }
}

// ---------------- GEMM: C = A(MxK) * B(NxK)^T + bias, LeakyReLU ----------------
// R13 skeleton + software-pipelined reads (named dbuf reg sets, rule 20):
// every read batch issues BEFORE an MFMA cluster that covers its latency;
// LGKM0 appears ONLY as the pre-barrier read-pin (WAR safety: no in-flight
// read may cross a barrier, since the next STG overwrites its source slot);
// MFMA consumes via compiler-emitted COUNTED lgkmcnt (no sched_barrier pins,
// no inline-asm ds_reads -> rule 18 n/a). 3 barriers/tile (P2's dropped;
// visibility: B1(kt)<-BARR#1, A1(kt)<-BARR#2, A0,B0(kt+1)<-BARR#3).
// VM ledger (simulated, closes): steady Q after BARR#3 = [B1,A1]; P0: +A0'
// VM4 drains B1; P1: +B0' VM4 drains A1; P2/P3: +B1',+A1' VM4 drains A0',B0'.
// Last tile: VM2 / VM0, BARR#3 dropped. 256x256 tile, BK=64, 8 waves (2Mx4N),
// 16x16x32 MFMA, interleaved frags; swizzle g ^= (row>>1)&7 src-pre-swizzled
// (0-conflict verified); XCD-bijective block swizzle; scalar epilogue.

#define BARR  __builtin_amdgcn_s_barrier()
#define VMW(N) asm volatile("s_waitcnt vmcnt(" #N ")" ::: "memory")
#define LGKM0 asm volatile("s_waitcnt lgkmcnt(0)" ::: "memory")
#define FENCE asm volatile("" ::: "memory")

// stage half-tile: ISA=1 -> A, h = row-half; dest linear, src col pre-swizzled
#define STG(kt, ISA, h)                                                        \
  do {                                                                         \
    const u16* _s = (ISA) ? gA : gB;                                           \
    u16* _d = smem + ((ISA) ? 0 : 32768) + (((kt) & 1) << 14) + ((h) << 13)    \
              + wave * 512;                                                    \
    const size_t _go = (size_t)((h) * 128) * K + (size_t)(kt) * 64;            \
    gload16(_s + _go,                 _d);                                     \
    gload16(_s + _go + (size_t)64 * K, _d + 4096);                             \
  } while (0)

#define RD_A(kt, mh, DST)                                                      \
  do {                                                                         \
    const u16* _p = smem + (((kt) & 1) << 14) + ((mh) << 13) + rowA;           \
    _Pragma("unroll") for (int m2 = 0; m2 < 4; ++m2) {                         \
        DST[m2 * 2]     = *(const bf16x8*)(_p + m2 * 2048 + g0);               \
        DST[m2 * 2 + 1] = *(const bf16x8*)(_p + m2 * 2048 + g1);               \
    }                                                                          \
  } while (0)

#define RD_B(kt, nh, DST)                                                      \
  do {                                                                         \
    const u16* _p = smem + 32768 + (((kt) & 1) << 14) + ((nh) << 13) + rowB;   \
    _Pragma("unroll") for (int n2 = 0; n2 < 2; ++n2) {                         \
        DST[n2 * 2]     = *(const bf16x8*)(_p + n2 * 4096 + g0);               \
        DST[n2 * 2 + 1] = *(const bf16x8*)(_p + n2 * 4096 + g1);               \
    }                                                                          \
  } while (0)

#define MM(mh, nh, AS, BS)                                                     \
  do {                                                                         \
    __builtin_amdgcn_s_setprio(1);                                             \
    _Pragma("unroll") for (int m2 = 0; m2 < 4; ++m2)                           \
      _Pragma("unroll") for (int n2 = 0; n2 < 2; ++n2) {                       \
        acc[(mh)*4+m2][(nh)*2+n2] = __builtin_amdgcn_mfma_f32_16x16x32_bf16(   \
            AS[m2*2],     BS[n2*2],   acc[(mh)*4+m2][(nh)*2+n2], 0, 0, 0);     \
        acc[(mh)*4+m2][(nh)*2+n2] = __builtin_amdgcn_mfma_f32_16x16x32_bf16(   \
            AS[m2*2+1],   BS[n2*2+1], acc[(mh)*4+m2][(nh)*2+n2], 0, 0, 0);     \
      }                                                                        \
    __builtin_amdgcn_s_setprio(0);                                             \
  } while (0)

template<int BF16OUT>
__global__ __launch_bounds__(512, 2)
void gemm8x(const u16* __restrict__ A, const u16* __restrict__ B,
            const float* __restrict__ bias, void* __restrict__ Cv,
            int M, int Nn, int K)
{
    __shared__ __align__(128) u16 smem[65536];  // A: [0,32768) B: [32768,65536)

    const int tid  = threadIdx.x;
    const int lane = tid & 63;
    const int wave = tid >> 6;
    const int wm = wave >> 2;   // 0..1
    const int wn = wave & 3;    // 0..3

    // XCD-aware bijective swizzle (gridDim.x % 8 == 0)
    const int nbx = Nn >> 8;
    const int cpx = gridDim.x >> 3;
    const int swz = (blockIdx.x & 7) * cpx + (blockIdx.x >> 3);
    const int bn = (swz % nbx) << 8;
    const int bm = (swz / nbx) << 8;

    // staging source: thread t covers row (t>>3) of a 64-row chunk, granule t&7;
    // source granule pre-swizzled: (t&7) ^ ((r>>1)&7) == (t&7) ^ ((t>>4)&7)
    const int scol = (((tid & 7) ^ ((tid >> 4) & 7)) << 3);
    const u16* gA = A + (size_t)(bm + (tid >> 3)) * K + scol;
    const u16* gB = B + (size_t)(bn + (tid >> 3)) * K + scol;

    // frag ds_read constants (u16 elems)
    const int fr = lane & 15;
    const int g0 = (((lane >> 4)    ) ^ (fr >> 1)) << 3;   // ks=0 granule
    const int g1 = (((lane >> 4) + 4) ^ (fr >> 1)) << 3;   // ks=1 granule
    const int rowA = (wm * 16 + fr) << 6;                  // + m2*2048 per m-frag
    const int rowB = (wn * 16 + fr) << 6;                  // + n2*4096 per n-frag

    f32x4 acc[8][4] = {};
    bf16x8 aA[8], aB[8], b0f[4], b1f[4];   // named dbuf sets (rule 20)

    const int NT = K >> 6;   // 16 or 32

    // prologue: tile 0's half-tiles in ledger order A0,B0,B1,A1;
    // VM4 certifies A0(0),B0(0) before P0's reads (R10 lesson).
    STG(0, 1, 0); STG(0, 0, 0); STG(0, 0, 1); STG(0, 1, 1);
    VMW(4);
    BARR; FENCE;

    for (int kt = 0; kt < NT - 1; ++kt) {
        // tile head: reads of A0,B0(kt) (certified by previous BARR)
        RD_A(kt, 0, aA); RD_B(kt, 0, b0f);
        STG(kt + 1, 1, 0);
        VMW(4);                 // certifies B1(kt)
        LGKM0;                  // pin reads (covered by STG issue + prev MM)
        BARR; FENCE;
        RD_B(kt, 1, b1f);       // issued under MM(0,0)
        MM(0, 0, aA, b0f);
        STG(kt + 1, 0, 0);
        VMW(4);                 // certifies A1(kt)
        LGKM0;                  // pin b1f reads (covered by MM(0,0))
        BARR; FENCE;
        RD_A(kt, 1, aB);        // issued under MM(0,1)/MM(1,0)
        MM(0, 1, aA, b1f);
        STG(kt + 1, 0, 1);
        MM(1, 0, aB, b0f);      // compiler counted lgkmcnt on aB
        STG(kt + 1, 1, 1);
        VMW(4);                 // certifies A0,B0(kt+1)
        LGKM0;                  // pin aB reads (covered by MM(0,1)+MM(1,0))
        BARR; FENCE;
        MM(1, 1, aB, b1f);      // next tile's reads interleave above this
    }
    {   // last tile: no staging; drain ledger [B1,A1]: 4 -> 2 -> 0
        const int kt = NT - 1;
        RD_A(kt, 0, aA); RD_B(kt, 0, b0f);
        VMW(2);                 // certifies B1
        LGKM0;
        BARR; FENCE;
        RD_B(kt, 1, b1f);
        MM(0, 0, aA, b0f);
        VMW(0);                 // certifies A1
        LGKM0;
        BARR; FENCE;
        RD_A(kt, 1, aB);
        MM(0, 1, aA, b1f);
        MM(1, 0, aB, b0f);
        MM(1, 1, aB, b1f);      // register deps; compiler counted waits
    }

    // ---- epilogue: scalar stores (R2/R8-proven) ----
    // C/D frag layout (m89): col = lane&15, row = (lane>>4)*4 + j
    // interleaved frag map: row = (m>>2)*128 + (m&3)*32 + wm*16; col = n*64 + wn*16
    const int crow = (lane >> 4) << 2;
    const int ccol = lane & 15;
    #pragma unroll
    for (int n = 0; n < 4; ++n) {
        const int col = bn + n * 64 + wn * 16 + ccol;
        const float bv = bias[col];
        #pragma unroll
        for (int m = 0; m < 8; ++m) {
            const int row0 = bm + (m >> 2) * 128 + (m & 3) * 32 + wm * 16 + crow;
            #pragma unroll
            for (int j = 0; j < 4; ++j) {
                float v = acc[m][n][j] + bv;
                v = (v >= 0.f) ? v : 0.01f * v;
                if (BF16OUT) {
                    ((u16*)Cv)[(size_t)(row0 + j) * Nn + col] = f2bf(v);
                } else {
                    ((float*)Cv)[(size_t)(row0 + j) * Nn + col] = v;
                }
            }
        }
    }
}

// ---------------- launch ----------------

extern "C" void kernel_launch(void* const* d_in, const int* in_sizes, int n_in,
                              void* d_out, int out_size, void* d_ws, size_t ws_size,
                              hipStream_t stream) {
    const float* x  = (const float*)d_in[0];
    const float* W0 = (const float*)d_in[1];
    const float* b0 = (const float*)d_in[2];
    const float* W1 = (const float*)d_in[3];
    const float* b1 = (const float*)d_in[4];
    const float* W2 = (const float*)d_in[5];
    const float* b2 = (const float*)d_in[6];

    const int N = 32768, D0 = 1024, D1 = 2048;

    char* ws = (char*)d_ws;
    u16* xbf = (u16*)ws;  ws += (size_t)N * D0 * 2;
    u16* h0  = (u16*)ws;  ws += (size_t)N * D1 * 2;
    u16* h1  = (u16*)ws;  ws += (size_t)N * D1 * 2;
    u16* w0q = (u16*)ws;  ws += (size_t)D1 * D0 * 2;
    u16* w1q = (u16*)ws;  ws += (size_t)D1 * D1 * 2;
    u16* w2q = (u16*)ws;  ws += (size_t)D1 * D1 * 2;
    unsigned int* scales = (unsigned int*)ws;

    zero3_k<<<1, 64, 0, stream>>>(scales);
    maxabs_k<<<256, 256, 0, stream>>>(W0, D1 * D0, scales + 0);
    maxabs_k<<<256, 256, 0, stream>>>(W1, D1 * D1, scales + 1);
    maxabs_k<<<256, 256, 0, stream>>>(W2, D1 * D1, scales + 2);
    quant_k<<<2048, 256, 0, stream>>>(W0, D1 * D0, scales + 0, 127.f, w0q);
    quant_k<<<2048, 256, 0, stream>>>(W1, D1 * D1, scales + 1, 7.f, w1q);
    quant_k<<<2048, 256, 0, stream>>>(W2, D1 * D1, scales + 2, 7.f, w2q);
    cvt_k<<<4096, 256, 0, stream>>>(x, xbf, (long)N * D0);

    const int blocks = (D1 / 256) * (N / 256);   // 8 * 128 = 1024, %8 == 0
    gemm8x<1><<<blocks, 512, 0, stream>>>(xbf, w0q, b0, h0, N, D1, D0);
    gemm8x<1><<<blocks, 512, 0, stream>>>(h0, w1q, b1, h1, N, D1, D1);
    gemm8x<0><<<blocks, 512, 0, stream>>>(h1, w2q, b2, d_out, N, D1, D1);
}

// Round 15
// 651.779 us; speedup vs baseline: 1.1237x; 1.1237x over previous
//
#include <hip/hip_runtime.h>
#include <hip/hip_bf16.h>
#include <stdint.h>

typedef __bf16 bf16x8 __attribute__((ext_vector_type(8)));
typedef float  f32x4  __attribute__((ext_vector_type(4)));
typedef unsigned short u16;

__device__ __forceinline__ u16 f2bf(float f) {
    return __builtin_bit_cast(u16, __float2bfloat16(f));
}

__device__ __forceinline__ void gload16(const void* g, void* l) {
    __builtin_amdgcn_global_load_lds(
        (const __attribute__((address_space(1))) void*)g,
        (__attribute__((address_space(3))) void*)l,
        16, 0, 0);
}

// ---------------- fused quantization pipeline (2 launches) ----------------
// Launch 1: per-weight partial maxes. 128 blocks per weight, each block owns a
// dedicated output slot -> no init kernel, no atomics, order-invariant (max).
__global__ void maxabs_all_k(const float* __restrict__ W0,
                             const float* __restrict__ W1,
                             const float* __restrict__ W2,
                             float* __restrict__ parts) {
    const int blk  = blockIdx.x;        // 0..383
    const int wsel = blk >> 7;          // 0,1,2
    const int lb   = blk & 127;
    const float* w = wsel == 0 ? W0 : (wsel == 1 ? W1 : W2);
    const int n4   = (wsel == 0 ? 2048 * 1024 : 2048 * 2048) >> 2;
    const int tid  = threadIdx.x;
    float m = 0.f;
    for (int i = lb * 256 + tid; i < n4; i += 128 * 256) {
        float4 v = ((const float4*)w)[i];
        m = fmaxf(m, fmaxf(fmaxf(fabsf(v.x), fabsf(v.y)),
                           fmaxf(fabsf(v.z), fabsf(v.w))));
    }
    #pragma unroll
    for (int off = 32; off > 0; off >>= 1)
        m = fmaxf(m, __shfl_down(m, off));
    __shared__ float red[4];
    if ((tid & 63) == 0) red[tid >> 6] = m;
    __syncthreads();
    if (tid == 0)
        parts[wsel * 128 + lb] = fmaxf(fmaxf(red[0], red[1]),
                                       fmaxf(red[2], red[3]));
}

// Launch 2: quantize all 3 weights (per-block redundant reduce of the 128
// partials -> identical fp32 scale in every block; same rintf/clip/*scale
// math as the proven per-weight kernels) + bf16-convert x. All float4 loads.
__global__ void prep_all_k(const float* __restrict__ W0,
                           const float* __restrict__ W1,
                           const float* __restrict__ W2,
                           const float* __restrict__ x,
                           const float* __restrict__ parts,
                           u16* __restrict__ w0q, u16* __restrict__ w1q,
                           u16* __restrict__ w2q, u16* __restrict__ xbf) {
    const int blk = blockIdx.x;
    const int tid = threadIdx.x;

    if (blk >= 2560) {   // ---- cvt segment: x -> bf16 (4096 blocks) ----
        const long n4 = (long)(32768) * 1024 / 4;
        for (long i = (long)(blk - 2560) * 256 + tid; i < n4;
             i += (long)4096 * 256) {
            float4 v = ((const float4*)x)[i];
            unsigned int lo = (unsigned int)f2bf(v.x) | ((unsigned int)f2bf(v.y) << 16);
            unsigned int hi = (unsigned int)f2bf(v.z) | ((unsigned int)f2bf(v.w) << 16);
            ((uint2*)xbf)[i] = make_uint2(lo, hi);
        }
        return;
    }

    int wsel, b0, nb; const float* w; u16* o; float qn;
    if (blk < 512)       { wsel = 0; b0 = 0;    nb = 512;  w = W0; o = w0q; qn = 127.f; }
    else if (blk < 1536) { wsel = 1; b0 = 512;  nb = 1024; w = W1; o = w1q; qn = 7.f; }
    else                 { wsel = 2; b0 = 1536; nb = 1024; w = W2; o = w2q; qn = 7.f; }

    // block-local reduce of this weight's 128 partials (identical in every block)
    float m = (tid < 128) ? parts[wsel * 128 + tid] : 0.f;
    #pragma unroll
    for (int off = 32; off > 0; off >>= 1)
        m = fmaxf(m, __shfl_down(m, off));
    __shared__ float red[4];
    if ((tid & 63) == 0) red[tid >> 6] = m;
    __syncthreads();
    const float scale = fmaxf(fmaxf(red[0], red[1]), fmaxf(red[2], red[3])) / qn;

    const int n4 = (wsel == 0 ? 2048 * 1024 : 2048 * 2048) >> 2;
    for (int i = (blk - b0) * 256 + tid; i < n4; i += nb * 256) {
        float4 v = ((const float4*)w)[i];
        float q0 = fminf(qn, fmaxf(-qn, rintf(v.x / scale)));   // RNE == jnp.round
        float q1 = fminf(qn, fmaxf(-qn, rintf(v.y / scale)));
        float q2 = fminf(qn, fmaxf(-qn, rintf(v.z / scale)));
        float q3 = fminf(qn, fmaxf(-qn, rintf(v.w / scale)));
        unsigned int lo = (unsigned int)f2bf(q0 * scale) | ((unsigned int)f2bf(q1 * scale) << 16);
        unsigned int hi = (unsigned int)f2bf(q2 * scale) | ((unsigned int)f2bf(q3 * scale) << 16);
        ((uint2*)o)[i] = make_uint2(lo, hi);
    }
}

// ---------------- GEMM: C = A(MxK) * B(NxK)^T + bias, LeakyReLU ----------------
// FROZEN R13 structure (best: 245us/gemm, 1122 TF, MfmaUtil 48, conflicts 0):
// 256x256 tile, BK=64, 8 waves (2M x 4N), 16x16x32 MFMA, interleaved frags,
// 4 quadrant phases per K-64 tile, mid-phase barriers only (tail barriers
// removed -> cross-wave drift/overlap), VM4 ledger (prologue certifies
// A0,B0(0); P0->B1; P1->A1; P3->A0,B0(kt+1)), swizzle g^=(row>>1)&7 with
// pre-swizzled global source (rule 21), XCD-bijective block swizzle.

#define BARR  __builtin_amdgcn_s_barrier()
#define VM4   asm volatile("s_waitcnt vmcnt(4)" ::: "memory")
#define LGKM0 do { asm volatile("s_waitcnt lgkmcnt(0)" ::: "memory");          \
                   __builtin_amdgcn_sched_barrier(0); } while (0)
#define FENCE asm volatile("" ::: "memory")

#define STG(kt, ISA, h)                                                        \
  do {                                                                         \
    const u16* _s = (ISA) ? gA : gB;                                           \
    u16* _d = smem + ((ISA) ? 0 : 32768) + (((kt) & 1) << 14) + ((h) << 13)    \
              + wave * 512;                                                    \
    const size_t _go = (size_t)((h) * 128) * K + (size_t)(kt) * 64;            \
    gload16(_s + _go,                 _d);                                     \
    gload16(_s + _go + (size_t)64 * K, _d + 4096);                             \
  } while (0)

#define RD_A(kt, mh)                                                           \
  do {                                                                         \
    const u16* _p = smem + (((kt) & 1) << 14) + ((mh) << 13) + rowA;           \
    _Pragma("unroll") for (int m2 = 0; m2 < 4; ++m2) {                         \
        afr[m2 * 2]     = *(const bf16x8*)(_p + m2 * 2048 + g0);               \
        afr[m2 * 2 + 1] = *(const bf16x8*)(_p + m2 * 2048 + g1);               \
    }                                                                          \
  } while (0)

#define RD_B(kt, nh, DST)                                                      \
  do {                                                                         \
    const u16* _p = smem + 32768 + (((kt) & 1) << 14) + ((nh) << 13) + rowB;   \
    _Pragma("unroll") for (int n2 = 0; n2 < 2; ++n2) {                         \
        DST[n2 * 2]     = *(const bf16x8*)(_p + n2 * 4096 + g0);               \
        DST[n2 * 2 + 1] = *(const bf16x8*)(_p + n2 * 4096 + g1);               \
    }                                                                          \
  } while (0)

#define MM(mh, nh, BS)                                                         \
  do {                                                                         \
    __builtin_amdgcn_s_setprio(1);                                             \
    _Pragma("unroll") for (int m2 = 0; m2 < 4; ++m2)                           \
      _Pragma("unroll") for (int n2 = 0; n2 < 2; ++n2) {                       \
        acc[(mh)*4+m2][(nh)*2+n2] = __builtin_amdgcn_mfma_f32_16x16x32_bf16(   \
            afr[m2*2],     BS[n2*2],   acc[(mh)*4+m2][(nh)*2+n2], 0, 0, 0);    \
        acc[(mh)*4+m2][(nh)*2+n2] = __builtin_amdgcn_mfma_f32_16x16x32_bf16(   \
            afr[m2*2+1],   BS[n2*2+1], acc[(mh)*4+m2][(nh)*2+n2], 0, 0, 0);    \
      }                                                                        \
    __builtin_amdgcn_s_setprio(0);                                             \
  } while (0)

template<int BF16OUT>
__global__ __launch_bounds__(512, 2)
void gemm8x(const u16* __restrict__ A, const u16* __restrict__ B,
            const float* __restrict__ bias, void* __restrict__ Cv,
            int M, int Nn, int K)
{
    __shared__ __align__(128) u16 smem[65536];  // A: [0,32768) B: [32768,65536)

    const int tid  = threadIdx.x;
    const int lane = tid & 63;
    const int wave = tid >> 6;
    const int wm = wave >> 2;   // 0..1
    const int wn = wave & 3;    // 0..3

    // XCD-aware bijective swizzle (gridDim.x % 8 == 0)
    const int nbx = Nn >> 8;
    const int cpx = gridDim.x >> 3;
    const int swz = (blockIdx.x & 7) * cpx + (blockIdx.x >> 3);
    const int bn = (swz % nbx) << 8;
    const int bm = (swz / nbx) << 8;

    // staging source: thread t covers row (t>>3) of a 64-row chunk, granule t&7;
    // source granule pre-swizzled: (t&7) ^ ((r>>1)&7) == (t&7) ^ ((t>>4)&7)
    const int scol = (((tid & 7) ^ ((tid >> 4) & 7)) << 3);
    const u16* gA = A + (size_t)(bm + (tid >> 3)) * K + scol;
    const u16* gB = B + (size_t)(bn + (tid >> 3)) * K + scol;

    // frag ds_read constants (u16 elems)
    const int fr = lane & 15;
    const int g0 = (((lane >> 4)    ) ^ (fr >> 1)) << 3;   // ks=0 granule
    const int g1 = (((lane >> 4) + 4) ^ (fr >> 1)) << 3;   // ks=1 granule
    const int rowA = (wm * 16 + fr) << 6;                  // + m2*2048 per m-frag
    const int rowB = (wn * 16 + fr) << 6;                  // + n2*4096 per n-frag

    f32x4 acc[8][4] = {};
    bf16x8 afr[8], b0f[4], b1f[4];

    const int NT = K >> 6;   // 16 or 32

    // prologue: tile 0's half-tiles in ledger order A0,B0,B1,A1;
    // VM4 certifies A0(0),B0(0) before P0's reads (R10 lesson).
    STG(0, 1, 0); STG(0, 0, 0); STG(0, 0, 1); STG(0, 1, 1);
    VM4;
    BARR;

    for (int kt = 0; kt < NT - 1; ++kt) {
        // P0: quadrant (0,0)
        RD_A(kt, 0); RD_B(kt, 0, b0f);
        STG(kt + 1, 1, 0);
        VM4; BARR; LGKM0;           // VM4 certifies B1(kt)
        MM(0, 0, b0f);
        FENCE;
        // P1: quadrant (0,1)
        RD_B(kt, 1, b1f);
        STG(kt + 1, 0, 0);
        VM4; BARR; LGKM0;           // VM4 certifies A1(kt)
        MM(0, 1, b1f);
        FENCE;
        // P2: quadrant (1,0)
        RD_A(kt, 1);
        STG(kt + 1, 0, 1);
        BARR; LGKM0;
        MM(1, 0, b0f);
        FENCE;
        // P3: quadrant (1,1)
        STG(kt + 1, 1, 1);
        VM4; BARR;                  // VM4 certifies A0(kt+1),B0(kt+1)
        __builtin_amdgcn_sched_barrier(0);
        MM(1, 1, b1f);
        FENCE;
    }
    {   // last tile: no staging; drain ledger 4 -> 2 -> 0
        const int kt = NT - 1;
        RD_A(kt, 0); RD_B(kt, 0, b0f);
        asm volatile("s_waitcnt vmcnt(2)" ::: "memory");   // certifies B1
        BARR; LGKM0;
        MM(0, 0, b0f);
        FENCE;
        RD_B(kt, 1, b1f);
        asm volatile("s_waitcnt vmcnt(0)" ::: "memory");   // certifies A1
        BARR; LGKM0;
        MM(0, 1, b1f);
        FENCE;
        RD_A(kt, 1);
        BARR; LGKM0;
        MM(1, 0, b0f);
        FENCE;
        __builtin_amdgcn_sched_barrier(0);
        MM(1, 1, b1f);
    }

    // ---- epilogue: scalar stores (R2/R8-proven) ----
    // C/D frag layout (m89): col = lane&15, row = (lane>>4)*4 + j
    // interleaved frag map: row = (m>>2)*128 + (m&3)*32 + wm*16; col = n*64 + wn*16
    const int crow = (lane >> 4) << 2;
    const int ccol = lane & 15;
    #pragma unroll
    for (int n = 0; n < 4; ++n) {
        const int col = bn + n * 64 + wn * 16 + ccol;
        const float bv = bias[col];
        #pragma unroll
        for (int m = 0; m < 8; ++m) {
            const int row0 = bm + (m >> 2) * 128 + (m & 3) * 32 + wm * 16 + crow;
            #pragma unroll
            for (int j = 0; j < 4; ++j) {
                float v = acc[m][n][j] + bv;
                v = (v >= 0.f) ? v : 0.01f * v;
                if (BF16OUT) {
                    ((u16*)Cv)[(size_t)(row0 + j) * Nn + col] = f2bf(v);
                } else {
                    ((float*)Cv)[(size_t)(row0 + j) * Nn + col] = v;
                }
            }
        }
    }
}

// ---------------- launch ----------------

extern "C" void kernel_launch(void* const* d_in, const int* in_sizes, int n_in,
                              void* d_out, int out_size, void* d_ws, size_t ws_size,
                              hipStream_t stream) {
    const float* x  = (const float*)d_in[0];
    const float* W0 = (const float*)d_in[1];
    const float* b0 = (const float*)d_in[2];
    const float* W1 = (const float*)d_in[3];
    const float* b1 = (const float*)d_in[4];
    const float* W2 = (const float*)d_in[5];
    const float* b2 = (const float*)d_in[6];

    const int N = 32768, D0 = 1024, D1 = 2048;

    char* ws = (char*)d_ws;
    u16* xbf = (u16*)ws;  ws += (size_t)N * D0 * 2;
    u16* h0  = (u16*)ws;  ws += (size_t)N * D1 * 2;
    u16* h1  = (u16*)ws;  ws += (size_t)N * D1 * 2;
    u16* w0q = (u16*)ws;  ws += (size_t)D1 * D0 * 2;
    u16* w1q = (u16*)ws;  ws += (size_t)D1 * D1 * 2;
    u16* w2q = (u16*)ws;  ws += (size_t)D1 * D1 * 2;
    float* parts = (float*)ws;   // 384 floats, fully rewritten each call

    maxabs_all_k<<<384, 256, 0, stream>>>(W0, W1, W2, parts);
    prep_all_k<<<6656, 256, 0, stream>>>(W0, W1, W2, x, parts,
                                         w0q, w1q, w2q, xbf);

    const int blocks = (D1 / 256) * (N / 256);   // 8 * 128 = 1024, %8 == 0
    gemm8x<1><<<blocks, 512, 0, stream>>>(xbf, w0q, b0, h0, N, D1, D0);
    gemm8x<1><<<blocks, 512, 0, stream>>>(h0, w1q, b1, h1, N, D1, D1);
    gemm8x<0><<<blocks, 512, 0, stream>>>(h1, w2q, b2, d_out, N, D1, D1);
}